// Round 8
// baseline (206.824 us; speedup 1.0000x reference)
//
#include <hip/hip_runtime.h>

// PhraseClassifier, three-phase, atomic-free:
//   K1: persistent waves, 4 row-pairs/wave, depth-1 software prefetch.
//       fwd/bwd half-row dots over all (pos,bid) rows -> tab (256KB in ws)
//   K2: grid-stride span lookup + sigmoid + BCE -> 200 block partials
//   K3: reduce partials -> out[0]
// hidden: (2048, 16, 1024) f32; spans: 200000; out: 1 f32 scalar.

#define HIDD 512
#define FEAT 1024
#define NROWS (2048 * 16)
#define K1_BLOCKS 1024                 // 4096 waves; 16384 pairs -> 4 pairs/wave
#define K1_STRIDE (K1_BLOCKS * 4)      // pair stride between a wave's pairs
#define K2_BLOCKS 200
#define K2_BLOCK 256

__device__ __forceinline__ float dot4(float4 a, float4 w) {
    return a.x * w.x + a.y * w.y + a.z * w.z + a.w * w.w;
}

__device__ __forceinline__ float wave_reduce(float v) {
    #pragma unroll
    for (int off = 32; off >= 1; off >>= 1)
        v += __shfl_xor(v, off, 64);
    return v;
}

// Load both half-rows of row-pair P (rows 2P, 2P+1): 8 independent dwordx4.
#define LOADP(P, A0, A1, A2, A3, B0, B1, B2, B3)                               \
    {                                                                          \
        const float4* _r0 = reinterpret_cast<const float4*>(                   \
            hidden + (size_t)(2 * (P)) * FEAT);                                \
        const float4* _r1 = _r0 + (FEAT / 4);                                  \
        A0 = _r0[lane];       A1 = _r0[64 + lane];                             \
        A2 = _r0[128 + lane]; A3 = _r0[192 + lane];                            \
        B0 = _r1[lane];       B1 = _r1[64 + lane];                             \
        B2 = _r1[128 + lane]; B3 = _r1[192 + lane];                            \
    }

// FMA + 7-shfl lane-specialized reduce + masked store for one row-pair.
__device__ __forceinline__ void compute_pair(
    float4 a0, float4 a1, float4 a2, float4 a3,
    float4 b0, float4 b1, float4 b2, float4 b3,
    float4 w0, float4 w1, float4 w2, float4 w3,
    int lane, float* __restrict__ tab, int nrows, int row)
{
    const float v0 = dot4(a0, w0) + dot4(a1, w1);   // fwd(row)
    const float v1 = dot4(a2, w2) + dot4(a3, w3);   // bwd(row)
    const float v2 = dot4(b0, w0) + dot4(b1, w1);   // fwd(row+1)
    const float v3 = dot4(b2, w2) + dot4(b3, w3);   // bwd(row+1)

    const bool s0 = (lane & 1) != 0;
    float x  = s0 ? v2 : v0;
    float y  = s0 ? v0 : v2;
    x += __shfl_xor(y, 1, 64);
    float u  = s0 ? v3 : v1;
    float w_ = s0 ? v1 : v3;
    u += __shfl_xor(w_, 1, 64);

    const bool s1 = (lane & 2) != 0;
    float p = s1 ? u : x;
    float q = s1 ? x : u;
    p += __shfl_xor(q, 2, 64);

    p += __shfl_xor(p, 4, 64);
    p += __shfl_xor(p, 8, 64);
    p += __shfl_xor(p, 16, 64);
    p += __shfl_xor(p, 32, 64);

    // lane0=fwd(row), lane1=fwd(row+1), lane2=bwd(row), lane3=bwd(row+1)
    if (lane < 4) {
        const int idx = (lane & 2) ? (nrows + row + (lane & 1))
                                   : (row + (lane & 1));
        tab[idx] = p;
    }
}

// ---------------- Kernel 1: row dot table, pipelined ----------------
__global__ __launch_bounds__(256) void row_dot_kernel(
    const float* __restrict__ hidden,
    const float* __restrict__ W,
    float*       __restrict__ tab,     // [2*NROWS]: fwd dots then bwd dots
    int nrows)
{
    const int lane  = threadIdx.x & 63;
    const int wid   = threadIdx.x >> 6;
    const int gwave = blockIdx.x * 4 + wid;   // 0..4095

    const float4* W4 = reinterpret_cast<const float4*>(W);
    const float4 w0 = W4[lane];
    const float4 w1 = W4[64 + lane];
    const float4 w2 = W4[128 + lane];
    const float4 w3 = W4[192 + lane];

    const int p0 = gwave;                 // 4 pairs: p0 + k*K1_STRIDE, k=0..3
    const int p1 = gwave + K1_STRIDE;
    const int p2 = gwave + 2 * K1_STRIDE;
    const int p3 = gwave + 3 * K1_STRIDE;

    float4 ca0, ca1, ca2, ca3, cb0, cb1, cb2, cb3;   // current pair
    float4 na0, na1, na2, na3, nb0, nb1, nb2, nb3;   // next pair (in flight)

    LOADP(p0, ca0, ca1, ca2, ca3, cb0, cb1, cb2, cb3);

    LOADP(p1, na0, na1, na2, na3, nb0, nb1, nb2, nb3);
    compute_pair(ca0, ca1, ca2, ca3, cb0, cb1, cb2, cb3,
                 w0, w1, w2, w3, lane, tab, nrows, 2 * p0);

    LOADP(p2, ca0, ca1, ca2, ca3, cb0, cb1, cb2, cb3);
    compute_pair(na0, na1, na2, na3, nb0, nb1, nb2, nb3,
                 w0, w1, w2, w3, lane, tab, nrows, 2 * p1);

    LOADP(p3, na0, na1, na2, na3, nb0, nb1, nb2, nb3);
    compute_pair(ca0, ca1, ca2, ca3, cb0, cb1, cb2, cb3,
                 w0, w1, w2, w3, lane, tab, nrows, 2 * p2);

    compute_pair(na0, na1, na2, na3, nb0, nb1, nb2, nb3,
                 w0, w1, w2, w3, lane, tab, nrows, 2 * p3);
}

// ---------------- Kernel 2: span lookup + BCE -> block partials ----------------
__global__ __launch_bounds__(K2_BLOCK) void span_bce_kernel(
    const float* __restrict__ tab,
    const int*   __restrict__ bids,
    const int*   __restrict__ begins,
    const int*   __restrict__ ends,
    const float* __restrict__ targets,
    const float* __restrict__ bias_p,
    float*       __restrict__ partials,
    int nspans, int nrows)
{
    const float bias = bias_p[0];
    float acc = 0.0f;

    for (int i = blockIdx.x * K2_BLOCK + threadIdx.x; i < nspans;
         i += K2_BLOCKS * K2_BLOCK) {
        const int   bid = bids[i];
        const int   fr  = (begins[i] - 1) * 16 + bid;
        const int   br  = ends[i] * 16 + bid;
        const float t   = targets[i];

        const float z  = tab[fr] + tab[nrows + br] + bias;
        const float p  = 1.0f / (1.0f + expf(-z));
        const float pc = fminf(fmaxf(p, 1e-12f), 1.0f);
        const float qc = fminf(fmaxf(1.0f - p, 1e-12f), 1.0f);
        acc += -(t * logf(pc) + (1.0f - t) * logf(qc));
    }

    acc = wave_reduce(acc);

    __shared__ float sacc[K2_BLOCK / 64];
    const int lane = threadIdx.x & 63;
    const int wid  = threadIdx.x >> 6;
    if (lane == 0) sacc[wid] = acc;
    __syncthreads();
    if (threadIdx.x == 0) {
        float s = 0.0f;
        #pragma unroll
        for (int k = 0; k < K2_BLOCK / 64; ++k) s += sacc[k];
        partials[blockIdx.x] = s;
    }
}

// ---------------- Kernel 3: reduce partials -> out ----------------
__global__ __launch_bounds__(256) void final_reduce_kernel(
    const float* __restrict__ partials,
    float*       __restrict__ out,
    int n, float inv_n)
{
    float acc = 0.0f;
    for (int i = threadIdx.x; i < n; i += 256)
        acc += partials[i];
    acc = wave_reduce(acc);

    __shared__ float sacc[4];
    const int lane = threadIdx.x & 63;
    const int wid  = threadIdx.x >> 6;
    if (lane == 0) sacc[wid] = acc;
    __syncthreads();
    if (threadIdx.x == 0)
        out[0] = (sacc[0] + sacc[1] + sacc[2] + sacc[3]) * inv_n;
}

// ---------------- Fallback (round-1 single kernel) ----------------
__global__ __launch_bounds__(256) void phrase_cls_fallback(
    const float* __restrict__ hidden,
    const int*   __restrict__ bids,
    const int*   __restrict__ begins,
    const int*   __restrict__ ends,
    const float* __restrict__ targets,
    const float* __restrict__ W,
    const float* __restrict__ bias_p,
    float*       __restrict__ out,
    int nspans, float inv_n)
{
    const int lane  = threadIdx.x & 63;
    const int wid   = threadIdx.x >> 6;
    const int gwave = blockIdx.x * 4 + wid;
    const int nwaves = gridDim.x * 4;

    const float4* W4 = reinterpret_cast<const float4*>(W);
    const float4 w0 = W4[lane];
    const float4 w1 = W4[64 + lane];
    const float4 w2 = W4[128 + lane];
    const float4 w3 = W4[192 + lane];
    const float bias = bias_p[0];

    float acc = 0.0f;
    for (int s = gwave; s < nspans; s += nwaves) {
        const int   bid = bids[s];
        const int   beg = begins[s] - 1;
        const int   end = ends[s];
        const float t   = targets[s];
        const float4* frow = reinterpret_cast<const float4*>(
            hidden + ((size_t)beg * 16 + (size_t)bid) * FEAT);
        const float4* brow = reinterpret_cast<const float4*>(
            hidden + ((size_t)end * 16 + (size_t)bid) * FEAT + HIDD);
        float d = dot4(frow[lane], w0) + dot4(frow[64 + lane], w1)
                + dot4(brow[lane], w2) + dot4(brow[64 + lane], w3);
        d = wave_reduce(d);
        if (lane == 0) {
            const float z  = d + bias;
            const float p  = 1.0f / (1.0f + expf(-z));
            const float pc = fminf(fmaxf(p, 1e-12f), 1.0f);
            const float qc = fminf(fmaxf(1.0f - p, 1e-12f), 1.0f);
            acc += -(t * logf(pc) + (1.0f - t) * logf(qc));
        }
    }
    __shared__ float sacc[4];
    if (lane == 0) sacc[wid] = acc;
    __syncthreads();
    if (threadIdx.x == 0) {
        float s = 0.0f;
        #pragma unroll
        for (int i = 0; i < 4; ++i) s += sacc[i];
        atomicAdd(out, s * inv_n);
    }
}

extern "C" void kernel_launch(void* const* d_in, const int* in_sizes, int n_in,
                              void* d_out, int out_size, void* d_ws, size_t ws_size,
                              hipStream_t stream) {
    const float* hidden  = (const float*)d_in[0];
    const int*   bids    = (const int*)  d_in[1];
    const int*   begins  = (const int*)  d_in[2];
    const int*   ends    = (const int*)  d_in[3];
    const float* targets = (const float*)d_in[4];
    const float* W       = (const float*)d_in[5];
    const float* b       = (const float*)d_in[6];
    float* out = (float*)d_out;

    const int nspans = in_sizes[1];
    const float inv_n = 1.0f / (float)nspans;

    const size_t need = ((size_t)2 * NROWS + (size_t)K2_BLOCKS) * sizeof(float);
    if (ws_size >= need) {
        float* tab      = (float*)d_ws;
        float* partials = tab + 2 * NROWS;
        // K1: persistent, 4 row-pairs/wave, depth-1 prefetch
        row_dot_kernel<<<K1_BLOCKS, 256, 0, stream>>>(hidden, W, tab, NROWS);
        // K2: grid-stride, 200 blocks -> 200 partials
        span_bce_kernel<<<K2_BLOCKS, K2_BLOCK, 0, stream>>>(
            tab, bids, begins, ends, targets, b, partials, nspans, NROWS);
        // K3: single block reduces partials, writes out directly
        final_reduce_kernel<<<1, 256, 0, stream>>>(partials, out, K2_BLOCKS, inv_n);
    } else {
        hipMemsetAsync(out, 0, sizeof(float), stream);
        phrase_cls_fallback<<<2048, 256, 0, stream>>>(
            hidden, bids, begins, ends, targets, W, b, out, nspans, inv_n);
    }
}